// Round 5
// baseline (2233.938 us; speedup 1.0000x reference)
//
#include <hip/hip_runtime.h>
#include <stdint.h>

#define N_PTS  16384
#define B_SZ   4
#define K_S    1024   // SAMPLE_NUM
#define K_N    32     // NEIGHBOR_NUM
#define C_FEAT 128

#define NCELL  512    // 8^3 Morton cells
// per-batch workspace: rx,ry,rz (f32) + orig (u16), 16-byte aligned sections
#define WS_PER_B_BYTES (N_PTS * (3 * 4 + 2))   // 229376, %16 == 0

// ---------------- Threefry-2x32 (JAX-compatible) ----------------
__device__ inline void threefry2x32(uint32_t k0, uint32_t k1,
                                    uint32_t x0, uint32_t x1,
                                    uint32_t& o0, uint32_t& o1) {
  uint32_t ks[3] = {k0, k1, k0 ^ k1 ^ 0x1BD11BDAu};
  const uint32_t rot[2][4] = {{13u, 15u, 26u, 6u}, {17u, 29u, 16u, 24u}};
  x0 += ks[0];
  x1 += ks[1];
#pragma unroll
  for (int i = 0; i < 5; ++i) {
    const uint32_t* r = rot[i & 1];
#pragma unroll
    for (int j = 0; j < 4; ++j) {
      x0 += x1;
      x1 = (x1 << r[j]) | (x1 >> (32u - r[j]));
      x1 ^= x0;
    }
    x0 += ks[(i + 1) % 3];
    x1 += ks[(i + 2) % 3] + (uint32_t)(i + 1);
  }
  o0 = x0;
  o1 = x1;
}

// jax.random.randint(key(42),(B,),0,N), threefry_partitionable:
// k2 = TF((0,42),(0,1)); bits[b] = fold(TF(k2,(0,b))); start = bits & 16383
__device__ inline int fps_start_index(int b) {
  uint32_t c0, c1, h0, h1;
  threefry2x32(0u, 42u, 0u, 1u, c0, c1);
  threefry2x32(c0, c1, 0u, (uint32_t)b, h0, h1);
  return (int)((h0 ^ h1) & (uint32_t)(N_PTS - 1));
}

// ---------------- Morton bucket sort: one block per batch ----------------
__device__ inline uint32_t expand3(uint32_t v) {  // 3-bit -> bits 0,3,6
  return (v & 1u) | ((v & 2u) << 2) | ((v & 4u) << 4);
}

__global__ __launch_bounds__(1024) void bucket_kernel(
    const float* __restrict__ xyz, float* __restrict__ ws) {
  const int b = blockIdx.x;
  const int t = threadIdx.x;
  const float* bx = xyz + (size_t)b * N_PTS * 3;
  float* rx = (float*)((char*)ws + (size_t)b * WS_PER_B_BYTES);
  float* ry = rx + N_PTS;
  float* rz = ry + N_PTS;
  unsigned short* ro = (unsigned short*)(rz + N_PTS);

  __shared__ unsigned int cnt[NCELL];
  __shared__ unsigned int scn[NCELL];

  if (t < NCELL) cnt[t] = 0;
  __syncthreads();

  unsigned short cell[16];
#pragma unroll
  for (int j = 0; j < 16; ++j) {
    const int p = t + j * 1024;  // coalesced
    const float x = bx[p * 3 + 0];
    const float y = bx[p * 3 + 1];
    const float z = bx[p * 3 + 2];
    int ix = (int)(x * 8.0f); ix = ix > 7 ? 7 : (ix < 0 ? 0 : ix);
    int iy = (int)(y * 8.0f); iy = iy > 7 ? 7 : (iy < 0 ? 0 : iy);
    int iz = (int)(z * 8.0f); iz = iz > 7 ? 7 : (iz < 0 ? 0 : iz);
    const uint32_t code =
        expand3((uint32_t)ix) | (expand3((uint32_t)iy) << 1) |
        (expand3((uint32_t)iz) << 2);
    cell[j] = (unsigned short)code;
    atomicAdd(&cnt[code], 1u);
  }
  __syncthreads();

  // exclusive prefix sum over 512 counts (Hillis-Steele)
  unsigned int v0 = 0;
  if (t < NCELL) { v0 = cnt[t]; scn[t] = v0; }
  __syncthreads();
  for (int d = 1; d < NCELL; d <<= 1) {
    unsigned int add = 0;
    if (t < NCELL && t >= d) add = scn[t - d];
    __syncthreads();
    if (t < NCELL) scn[t] += add;
    __syncthreads();
  }
  if (t < NCELL) scn[t] -= v0;  // exclusive
  __syncthreads();

  // scatter (order within cell nondeterministic -- results invariant: the
  // FPS reduce is a commutative max over unique (value, ~orig_idx) keys)
#pragma unroll
  for (int j = 0; j < 16; ++j) {
    const int p = t + j * 1024;
    const unsigned int place = atomicAdd(&scn[cell[j]], 1u);
    rx[place] = bx[p * 3 + 0];
    ry[place] = bx[p * 3 + 1];
    rz[place] = bx[p * 3 + 2];
    ro[place] = (unsigned short)p;
  }
}

// ---------------- Bucketed FPS: one 1024-thread block per batch -----------
// NO global memory ops inside the iteration loop: winner coords ride the
// argmax reduces (LDS + shuffles only), samples buffered in LDS and flushed
// once at the end. This keeps the pre-barrier s_waitcnt to lgkmcnt-only.
#define FT  1024
#define PPT 16

__global__ __launch_bounds__(FT) void fps_kernel(
    const float* __restrict__ xyz, const float* __restrict__ ws,
    float* __restrict__ sample_xyz) {
  const int b = blockIdx.x;
  const int t = threadIdx.x;
  const int lane = t & 63;
  const int wv = t >> 6;  // 0..15
  const float* bx = xyz + (size_t)b * N_PTS * 3;
  const float* rx = (const float*)((const char*)ws + (size_t)b * WS_PER_B_BYTES);
  const float* ry = rx + N_PTS;
  const float* rz = ry + N_PTS;
  const unsigned short* ro = (const unsigned short*)(rz + N_PTS);

  float px[PPT], py[PPT], pz[PPT], md[PPT];
  const int base = t * PPT;
#pragma unroll
  for (int j = 0; j < PPT; ++j) {
    px[j] = rx[base + j];
    py[j] = ry[base + j];
    pz[j] = rz[base + j];
    md[j] = __int_as_float(0x7f800000);  // +inf
  }
  // packed original indices (2 x u16 per reg)
  uint32_t op[PPT / 2];
  {
    const uint4* rop = (const uint4*)(ro + base);  // 32B-aligned
    const uint4 o0 = rop[0], o1 = rop[1];
    op[0] = o0.x; op[1] = o0.y; op[2] = o0.z; op[3] = o0.w;
    op[4] = o1.x; op[5] = o1.y; op[6] = o1.z; op[7] = o1.w;
  }
  // tight per-thread bbox
  float bnx = px[0], bXx = px[0], bny = py[0], bXy = py[0],
        bnz = pz[0], bXz = pz[0];
#pragma unroll
  for (int j = 1; j < PPT; ++j) {
    bnx = fminf(bnx, px[j]); bXx = fmaxf(bXx, px[j]);
    bny = fminf(bny, py[j]); bXy = fmaxf(bXy, py[j]);
    bnz = fminf(bnz, pz[j]); bXz = fmaxf(bXz, pz[j]);
  }

  __shared__ unsigned long long wkey[2][FT / 64];
  __shared__ float4 wcoord[2][FT / 64];
  __shared__ float4 scoord[K_S];  // sample buffer, flushed once at the end

  {  // seed buffer 0: start index as winner, coords via one pre-loop load
    const int start = fps_start_index(b);
    if (t < FT / 64) {
      const float sx = bx[start * 3 + 0];  // same addr -> broadcast load
      const float sy = bx[start * 3 + 1];
      const float sz = bx[start * 3 + 2];
      wkey[0][t] = (0xFFFFFFFFull << 32) |
                   (unsigned long long)(0xFFFFFFFFu - (uint32_t)start);
      wcoord[0][t] = make_float4(sx, sy, sz, 0.f);
    }
  }
  float bestv = __int_as_float(0x7f800000);  // cached lane max(md) (forces upd)
  uint32_t besti = 0;
  float bpx = 0.f, bpy = 0.f, bpz = 0.f;     // cached lane-best coords
  unsigned long long kwave = 0;              // cached wave-reduced key
  float kcx = 0.f, kcy = 0.f, kcz = 0.f;     // cached wave-reduced coords
  __syncthreads();

  for (int s = 0; s < K_S; ++s) {
    const int rb = s & 1, wb = rb ^ 1;

    // cross-wave argmax with coords riding along (16 keys, 4 stages)
    unsigned long long k = wkey[rb][lane & 15];
    float4 c = wcoord[rb][lane & 15];
#pragma unroll
    for (int off = 1; off < 16; off <<= 1) {
      const unsigned long long ok = __shfl_xor(k, off, 64);
      const float ox = __shfl_xor(c.x, off, 64);
      const float oy = __shfl_xor(c.y, off, 64);
      const float oz = __shfl_xor(c.z, off, 64);
      const bool bt = ok > k;
      k = bt ? ok : k;
      c.x = bt ? ox : c.x;
      c.y = bt ? oy : c.y;
      c.z = bt ? oz : c.z;
    }
    const float cx = c.x, cy = c.y, cz = c.z;
    if (t == 0) scoord[s] = c;  // LDS sample buffer (fire-and-forget)

    // conservative squared lower bound to this thread's bbox
    const float dlx = fmaxf(fmaxf(__fsub_rn(bnx, cx), __fsub_rn(cx, bXx)), 0.f);
    const float dly = fmaxf(fmaxf(__fsub_rn(bny, cy), __fsub_rn(cy, bXy)), 0.f);
    const float dlz = fmaxf(fmaxf(__fsub_rn(bnz, cz), __fsub_rn(cz, bXz)), 0.f);
    const float lb = dlx * dlx + dly * dly + dlz * dlz;
    const bool upd = (lb * 0.999f) < bestv;  // exact skip (margin >> rounding)

    if (__any(upd)) {
      if (upd) {
        float bv = -1.0f;
        uint32_t bi = 0;
        float vx = 0.f, vy = 0.f, vz = 0.f;
#pragma unroll
        for (int j = 0; j < PPT; ++j) {
          const float dx = __fsub_rn(px[j], cx);
          const float dy = __fsub_rn(py[j], cy);
          const float dz = __fsub_rn(pz[j], cz);
          // XLA order: ((dx*dx + dy*dy) + dz*dz), no FMA contraction
          const float d2 = __fadd_rn(
              __fadd_rn(__fmul_rn(dx, dx), __fmul_rn(dy, dy)),
              __fmul_rn(dz, dz));
          const float m = fminf(md[j], d2);
          md[j] = m;
          const uint32_t orig =
              (j & 1) ? (op[j >> 1] >> 16) : (op[j >> 1] & 0xFFFFu);
          const bool better = (m > bv) | ((m == bv) & (orig < bi));
          bv = better ? m : bv;
          bi = better ? orig : bi;
          vx = better ? px[j] : vx;
          vy = better ? py[j] : vy;
          vz = better ? pz[j] : vz;
        }
        bestv = bv; besti = bi; bpx = vx; bpy = vy; bpz = vz;
      }
      // wave reduce over 64 lanes, coords riding along
      unsigned long long kk =
          ((unsigned long long)__float_as_uint(bestv) << 32) |
          (unsigned long long)(0xFFFFFFFFu - besti);
      float wx = bpx, wy = bpy, wz = bpz;
#pragma unroll
      for (int off = 1; off < 64; off <<= 1) {
        const unsigned long long ok = __shfl_xor(kk, off, 64);
        const float ox = __shfl_xor(wx, off, 64);
        const float oy = __shfl_xor(wy, off, 64);
        const float oz = __shfl_xor(wz, off, 64);
        const bool bt = ok > kk;
        kk = bt ? ok : kk;
        wx = bt ? ox : wx;
        wy = bt ? oy : wy;
        wz = bt ? oz : wz;
      }
      kwave = kk; kcx = wx; kcy = wy; kcz = wz;
    }
    if (lane == 0) {
      wkey[wb][wv] = kwave;
      wcoord[wb][wv] = make_float4(kcx, kcy, kcz, 0.f);
    }
    __syncthreads();  // lgkmcnt-only drain: no global ops in the loop
  }

  // flush sample buffer (once)
  {
    const float4 v = scoord[t];
    float* o = sample_xyz + ((size_t)b * K_S + t) * 3;
    o[0] = v.x; o[1] = v.y; o[2] = v.z;
  }
}

// ---------------- Ball query + gather: one wave per query ----------------
__global__ __launch_bounds__(256) void group_kernel(
    const float* __restrict__ xyz, const float* __restrict__ feat,
    const float* __restrict__ sample_xyz, float* __restrict__ out_feat) {
  const int lane = threadIdx.x & 63;
  const int wv = threadIdx.x >> 6;
  const int q = blockIdx.x * 4 + wv;  // 0..4095
  const int b = q >> 10;

  __shared__ int idxs[4][K_N];

  const float qx = sample_xyz[q * 3 + 0];
  const float qy = sample_xyz[q * 3 + 1];
  const float qz = sample_xyz[q * 3 + 2];
  const float* bx = xyz + (size_t)b * N_PTS * 3;
  const float R2 = (float)(0.2 * 0.2);  // f32 round of the Python double
  const unsigned long long below = (1ull << lane) - 1ull;

  int cnt = 0;
  for (int c = 0; c < N_PTS / 128 && cnt < K_N; ++c) {
    const int p0 = c * 128 + lane;
    const int p1 = p0 + 64;
    const float x0 = bx[p0 * 3 + 0], y0 = bx[p0 * 3 + 1], z0 = bx[p0 * 3 + 2];
    const float x1 = bx[p1 * 3 + 0], y1 = bx[p1 * 3 + 1], z1 = bx[p1 * 3 + 2];

    const float dx0 = __fsub_rn(qx, x0), dy0 = __fsub_rn(qy, y0),
                dz0 = __fsub_rn(qz, z0);
    const float d20 = __fadd_rn(
        __fadd_rn(__fmul_rn(dx0, dx0), __fmul_rn(dy0, dy0)),
        __fmul_rn(dz0, dz0));
    const float dx1 = __fsub_rn(qx, x1), dy1 = __fsub_rn(qy, y1),
                dz1 = __fsub_rn(qz, z1);
    const float d21 = __fadd_rn(
        __fadd_rn(__fmul_rn(dx1, dx1), __fmul_rn(dy1, dy1)),
        __fmul_rn(dz1, dz1));

    const bool h0 = d20 < R2;
    const bool h1 = d21 < R2;
    const unsigned long long m0 = __ballot(h0);
    const unsigned long long m1 = __ballot(h1);
    const int c0 = (int)__popcll(m0);
    if (h0) {
      const int slot = cnt + (int)__popcll(m0 & below);
      if (slot < K_N) idxs[wv][slot] = p0;
    }
    if (h1) {
      const int slot = cnt + c0 + (int)__popcll(m1 & below);
      if (slot < K_N) idxs[wv][slot] = p1;
    }
    cnt += c0 + (int)__popcll(m1);
  }
  // -1 padding semantics: gather_feat maps -1 -> row SAMPLE_NUM (=1024)
  if (cnt < K_N) {
    for (int s2 = cnt + lane; s2 < K_N; s2 += 64) idxs[wv][s2] = K_S;
  }
  __syncthreads();

  // gather feat rows -> out[(q*32 + k)*128 + c], float4 coalesced, full unroll
  const float4* f4 = (const float4*)feat;
  float4* o4 = (float4*)out_feat;
  const size_t fbase = (size_t)b * N_PTS * (C_FEAT / 4);
  const size_t obase = (size_t)q * K_N * (C_FEAT / 4);
  const int c4 = lane & 31;
  const int khalf = lane >> 5;
#pragma unroll
  for (int kk = 0; kk < K_N; kk += 2) {
    const int k = kk + khalf;
    const int id = idxs[wv][k];
    const float4 v = f4[fbase + (size_t)id * (C_FEAT / 4) + c4];
    o4[obase + (size_t)k * (C_FEAT / 4) + c4] = v;
  }
}

extern "C" void kernel_launch(void* const* d_in, const int* in_sizes, int n_in,
                              void* d_out, int out_size, void* d_ws,
                              size_t ws_size, hipStream_t stream) {
  const float* xyz = (const float*)d_in[0];
  const float* feat = (const float*)d_in[1];
  float* sample_xyz = (float*)d_out;
  float* out_feat = (float*)d_out + (size_t)B_SZ * K_S * 3;
  float* ws = (float*)d_ws;

  hipLaunchKernelGGL(bucket_kernel, dim3(B_SZ), dim3(1024), 0, stream, xyz, ws);
  hipLaunchKernelGGL(fps_kernel, dim3(B_SZ), dim3(FT), 0, stream, xyz, ws,
                     sample_xyz);
  hipLaunchKernelGGL(group_kernel, dim3((B_SZ * K_S) / 4), dim3(256), 0,
                     stream, xyz, feat, sample_xyz, out_feat);
}

// Round 6
// 1397.380 us; speedup vs baseline: 1.5987x; 1.5987x over previous
//
#include <hip/hip_runtime.h>
#include <stdint.h>

#define N_PTS  16384
#define B_SZ   4
#define K_S    1024   // SAMPLE_NUM
#define K_N    32     // NEIGHBOR_NUM
#define C_FEAT 128
#define NCELL  512    // 8^3 Morton cells

// per-batch ws layout: rxyzw float4[N] | ro u16[N] | inv u16[N]
#define WS_RXYZW_BYTES (N_PTS * 16)
#define WS_RO_OFF      WS_RXYZW_BYTES
#define WS_INV_OFF     (WS_RXYZW_BYTES + N_PTS * 2)
#define WS_PER_B_BYTES (WS_RXYZW_BYTES + N_PTS * 4)   // 327680, %16==0

// ---------------- Threefry-2x32 (JAX-compatible) ----------------
__device__ inline void threefry2x32(uint32_t k0, uint32_t k1,
                                    uint32_t x0, uint32_t x1,
                                    uint32_t& o0, uint32_t& o1) {
  uint32_t ks[3] = {k0, k1, k0 ^ k1 ^ 0x1BD11BDAu};
  const uint32_t rot[2][4] = {{13u, 15u, 26u, 6u}, {17u, 29u, 16u, 24u}};
  x0 += ks[0];
  x1 += ks[1];
#pragma unroll
  for (int i = 0; i < 5; ++i) {
    const uint32_t* r = rot[i & 1];
#pragma unroll
    for (int j = 0; j < 4; ++j) {
      x0 += x1;
      x1 = (x1 << r[j]) | (x1 >> (32u - r[j]));
      x1 ^= x0;
    }
    x0 += ks[(i + 1) % 3];
    x1 += ks[(i + 2) % 3] + (uint32_t)(i + 1);
  }
  o0 = x0;
  o1 = x1;
}

// jax.random.randint(key(42),(B,),0,N), threefry_partitionable:
// k2 = TF((0,42),(0,1)); bits[b] = fold(TF(k2,(0,b))); start = bits & 16383
__device__ inline int fps_start_index(int b) {
  uint32_t c0, c1, h0, h1;
  threefry2x32(0u, 42u, 0u, 1u, c0, c1);
  threefry2x32(c0, c1, 0u, (uint32_t)b, h0, h1);
  return (int)((h0 ^ h1) & (uint32_t)(N_PTS - 1));
}

// ---------------- DPP u64 max helpers (VALU pipe, no DS ops) --------------
template <int CTRL>
__device__ inline uint64_t dpp_max_u64(uint64_t k) {
  const int lo = (int)(uint32_t)k;
  const int hi = (int)(uint32_t)(k >> 32);
  // bound_ctrl=true: out-of-range lanes read 0 == identity (all keys > 0)
  const uint32_t slo =
      (uint32_t)__builtin_amdgcn_update_dpp(0, lo, CTRL, 0xF, 0xF, true);
  const uint32_t shi =
      (uint32_t)__builtin_amdgcn_update_dpp(0, hi, CTRL, 0xF, 0xF, true);
  const uint64_t s = ((uint64_t)shi << 32) | slo;
  return s > k ? s : k;
}

__device__ inline uint64_t readlane_u64(uint64_t k, int lane) {
  const uint32_t lo =
      (uint32_t)__builtin_amdgcn_readlane((int)(uint32_t)k, lane);
  const uint32_t hi =
      (uint32_t)__builtin_amdgcn_readlane((int)(uint32_t)(k >> 32), lane);
  return ((uint64_t)hi << 32) | lo;
}

// ---------------- Morton bucket sort: one block per batch ----------------
__device__ inline uint32_t expand3(uint32_t v) {  // 3-bit -> bits 0,3,6
  return (v & 1u) | ((v & 2u) << 2) | ((v & 4u) << 4);
}

__global__ __launch_bounds__(1024) void bucket_kernel(
    const float* __restrict__ xyz, char* __restrict__ ws) {
  const int b = blockIdx.x;
  const int t = threadIdx.x;
  const float* bx = xyz + (size_t)b * N_PTS * 3;
  char* wsb = ws + (size_t)b * WS_PER_B_BYTES;
  float4* rp = (float4*)wsb;
  unsigned short* ro = (unsigned short*)(wsb + WS_RO_OFF);
  unsigned short* inv = (unsigned short*)(wsb + WS_INV_OFF);

  __shared__ unsigned int cnt[NCELL];
  __shared__ unsigned int scn[NCELL];

  if (t < NCELL) cnt[t] = 0;
  __syncthreads();

  unsigned short cell[16];
#pragma unroll
  for (int j = 0; j < 16; ++j) {
    const int p = t + j * 1024;  // coalesced
    const float x = bx[p * 3 + 0];
    const float y = bx[p * 3 + 1];
    const float z = bx[p * 3 + 2];
    int ix = (int)(x * 8.0f); ix = ix > 7 ? 7 : (ix < 0 ? 0 : ix);
    int iy = (int)(y * 8.0f); iy = iy > 7 ? 7 : (iy < 0 ? 0 : iy);
    int iz = (int)(z * 8.0f); iz = iz > 7 ? 7 : (iz < 0 ? 0 : iz);
    const uint32_t code =
        expand3((uint32_t)ix) | (expand3((uint32_t)iy) << 1) |
        (expand3((uint32_t)iz) << 2);
    cell[j] = (unsigned short)code;
    atomicAdd(&cnt[code], 1u);
  }
  __syncthreads();

  // exclusive prefix sum over 512 counts
  unsigned int v0 = 0;
  if (t < NCELL) { v0 = cnt[t]; scn[t] = v0; }
  __syncthreads();
  for (int d = 1; d < NCELL; d <<= 1) {
    unsigned int add = 0;
    if (t < NCELL && t >= d) add = scn[t - d];
    __syncthreads();
    if (t < NCELL) scn[t] += add;
    __syncthreads();
  }
  if (t < NCELL) scn[t] -= v0;  // exclusive
  __syncthreads();

  // scatter; intra-cell order nondeterministic but FPS results are invariant:
  // keys carry orig idx (commutative max), and pruned updates are no-ops.
#pragma unroll
  for (int j = 0; j < 16; ++j) {
    const int p = t + j * 1024;
    const unsigned int place = atomicAdd(&scn[cell[j]], 1u);
    rp[place] = make_float4(bx[p * 3 + 0], bx[p * 3 + 1], bx[p * 3 + 2], 0.f);
    ro[place] = (unsigned short)p;
    inv[p] = (unsigned short)place;
  }
}

// ---------------- Bucketed FPS: one 1024-thread block per batch -----------
// DS-pipe-minimal loop: per wave per iteration only 1 ds_read_b64 (cross-wave
// keys) + 1 ds_write_b64 (publish). All reductions via DPP on the VALU pipe.
// Key = (md_bits:32 | ~orig:16 | reord:16) -> winner coords via one uniform
// float4 load (consumed before the barrier -> no vmcnt drain stall).
#define FT  1024
#define PPT 16

__global__ __launch_bounds__(FT, 4) void fps_kernel(
    const char* __restrict__ ws, float* __restrict__ sample_xyz) {
  const int b = blockIdx.x;
  const int t = threadIdx.x;
  const int lane = t & 63;
  const int wv = t >> 6;  // 0..15
  const char* wsb = ws + (size_t)b * WS_PER_B_BYTES;
  const float4* rp = (const float4*)wsb;
  const unsigned short* ro = (const unsigned short*)(wsb + WS_RO_OFF);
  const unsigned short* inv = (const unsigned short*)(wsb + WS_INV_OFF);

  float px[PPT], py[PPT], pz[PPT], md[PPT];
  uint32_t klo[PPT];  // precomputed key low word: (~orig:16 | reord:16)
  const int base = t * PPT;
#pragma unroll
  for (int j = 0; j < PPT; ++j) {
    const float4 v = rp[base + j];
    px[j] = v.x; py[j] = v.y; pz[j] = v.z;
    md[j] = __int_as_float(0x7f800000);  // +inf
    klo[j] = ((0xFFFFu ^ (uint32_t)ro[base + j]) << 16) | (uint32_t)(base + j);
  }
  // tight per-thread bbox (16 Morton-contiguous points)
  float bnx = px[0], bXx = px[0], bny = py[0], bXy = py[0],
        bnz = pz[0], bXz = pz[0];
#pragma unroll
  for (int j = 1; j < PPT; ++j) {
    bnx = fminf(bnx, px[j]); bXx = fmaxf(bXx, px[j]);
    bny = fminf(bny, py[j]); bXy = fmaxf(bXy, py[j]);
    bnz = fminf(bnz, pz[j]); bXz = fmaxf(bXz, pz[j]);
  }

  __shared__ uint64_t wkey[2][FT / 64];
  __shared__ float4 scoord[K_S];  // sample buffer, flushed once at the end

  if (t < FT / 64) {  // seed all 16 slots with the start point (md=+inf-ish)
    const int start = fps_start_index(b);
    const uint32_t sre = (uint32_t)inv[start];  // reordered position
    wkey[0][t] = ((uint64_t)0xFFFFFFFFu << 32) |
                 ((uint64_t)(0xFFFFu ^ (uint32_t)start) << 16) | sre;
  }
  float bestv = __int_as_float(0x7f800000);  // cached lane max(md): force upd
  uint64_t klane = 0;   // cached lane-best key
  uint64_t kwave = 0;   // cached wave-reduced key
  __syncthreads();

  for (int s = 0; s < K_S; ++s) {
    const int rb = s & 1, wb = rb ^ 1;

    // cross-wave argmax: 1 DS read + 4 DPP stages + readlane (VALU pipe)
    uint64_t k = wkey[rb][lane & 15];
    k = dpp_max_u64<0x111>(k);  // row_shr:1
    k = dpp_max_u64<0x112>(k);  // row_shr:2
    k = dpp_max_u64<0x114>(k);  // row_shr:4
    k = dpp_max_u64<0x118>(k);  // row_shr:8  -> lane15 of each row = max
    const uint64_t best = readlane_u64(k, 15);  // uniform
    const int wre = (int)(best & 0xFFFFu);      // winner's reordered index

    // uniform winner-coord load (L2/scalar-cache broadcast)
    const float4 c = rp[wre];
    if (t == 0) scoord[s] = c;
    const float cx = c.x, cy = c.y, cz = c.z;

    // conservative squared lower bound to this thread's bbox
    const float dlx = fmaxf(fmaxf(__fsub_rn(bnx, cx), __fsub_rn(cx, bXx)), 0.f);
    const float dly = fmaxf(fmaxf(__fsub_rn(bny, cy), __fsub_rn(cy, bXy)), 0.f);
    const float dlz = fmaxf(fmaxf(__fsub_rn(bnz, cz), __fsub_rn(cz, bXz)), 0.f);
    const float lb = dlx * dlx + dly * dly + dlz * dlz;
    const bool upd = (lb * 0.999f) < bestv;  // exact skip (margin >> rounding)

    if (__any(upd)) {
      if (upd) {
        uint64_t kk = 0;
#pragma unroll
        for (int j = 0; j < PPT; ++j) {
          const float dx = __fsub_rn(px[j], cx);
          const float dy = __fsub_rn(py[j], cy);
          const float dz = __fsub_rn(pz[j], cz);
          // XLA order: ((dx*dx + dy*dy) + dz*dz), no FMA contraction
          const float d2 = __fadd_rn(
              __fadd_rn(__fmul_rn(dx, dx), __fmul_rn(dy, dy)),
              __fmul_rn(dz, dz));
          const float m = fminf(md[j], d2);
          md[j] = m;
          const uint64_t key =
              ((uint64_t)__float_as_uint(m) << 32) | klo[j];
          kk = key > kk ? key : kk;
        }
        klane = kk;
        bestv = __uint_as_float((uint32_t)(kk >> 32));
      }
      // wave argmax over all 64 lanes' cached keys, pure DPP
      uint64_t r = klane;
      r = dpp_max_u64<0x111>(r);
      r = dpp_max_u64<0x112>(r);
      r = dpp_max_u64<0x114>(r);
      r = dpp_max_u64<0x118>(r);
      r = dpp_max_u64<0x142>(r);  // row_bcast15
      r = dpp_max_u64<0x143>(r);  // row_bcast31 -> lane63 = wave max
      kwave = readlane_u64(r, 63);
    }
    if (lane == 0) wkey[wb][wv] = kwave;
    __syncthreads();  // the one barrier; lgkmcnt-dominated drain
  }

  // flush sample buffer (once)
  {
    const float4 v = scoord[t];
    float* o = sample_xyz + ((size_t)b * K_S + t) * 3;
    o[0] = v.x; o[1] = v.y; o[2] = v.z;
  }
}

// ---------------- Ball query + gather: one wave per query ----------------
__global__ __launch_bounds__(256) void group_kernel(
    const float* __restrict__ xyz, const float* __restrict__ feat,
    const float* __restrict__ sample_xyz, float* __restrict__ out_feat) {
  const int lane = threadIdx.x & 63;
  const int wv = threadIdx.x >> 6;
  const int q = blockIdx.x * 4 + wv;  // 0..4095
  const int b = q >> 10;

  __shared__ int idxs[4][K_N];

  const float qx = sample_xyz[q * 3 + 0];
  const float qy = sample_xyz[q * 3 + 1];
  const float qz = sample_xyz[q * 3 + 2];
  const float* bx = xyz + (size_t)b * N_PTS * 3;
  const float R2 = (float)(0.2 * 0.2);  // f32 round of the Python double
  const unsigned long long below = (1ull << lane) - 1ull;

  int cnt = 0;
  for (int c = 0; c < N_PTS / 128 && cnt < K_N; ++c) {
    const int p0 = c * 128 + lane;
    const int p1 = p0 + 64;
    const float x0 = bx[p0 * 3 + 0], y0 = bx[p0 * 3 + 1], z0 = bx[p0 * 3 + 2];
    const float x1 = bx[p1 * 3 + 0], y1 = bx[p1 * 3 + 1], z1 = bx[p1 * 3 + 2];

    const float dx0 = __fsub_rn(qx, x0), dy0 = __fsub_rn(qy, y0),
                dz0 = __fsub_rn(qz, z0);
    const float d20 = __fadd_rn(
        __fadd_rn(__fmul_rn(dx0, dx0), __fmul_rn(dy0, dy0)),
        __fmul_rn(dz0, dz0));
    const float dx1 = __fsub_rn(qx, x1), dy1 = __fsub_rn(qy, y1),
                dz1 = __fsub_rn(qz, z1);
    const float d21 = __fadd_rn(
        __fadd_rn(__fmul_rn(dx1, dx1), __fmul_rn(dy1, dy1)),
        __fmul_rn(dz1, dz1));

    const bool h0 = d20 < R2;
    const bool h1 = d21 < R2;
    const unsigned long long m0 = __ballot(h0);
    const unsigned long long m1 = __ballot(h1);
    const int c0 = (int)__popcll(m0);
    if (h0) {
      const int slot = cnt + (int)__popcll(m0 & below);
      if (slot < K_N) idxs[wv][slot] = p0;
    }
    if (h1) {
      const int slot = cnt + c0 + (int)__popcll(m1 & below);
      if (slot < K_N) idxs[wv][slot] = p1;
    }
    cnt += c0 + (int)__popcll(m1);
  }
  // -1 padding semantics: gather_feat maps -1 -> row SAMPLE_NUM (=1024)
  if (cnt < K_N) {
    for (int s2 = cnt + lane; s2 < K_N; s2 += 64) idxs[wv][s2] = K_S;
  }
  __syncthreads();

  // gather feat rows -> out[(q*32 + k)*128 + c], float4 coalesced, full unroll
  const float4* f4 = (const float4*)feat;
  float4* o4 = (float4*)out_feat;
  const size_t fbase = (size_t)b * N_PTS * (C_FEAT / 4);
  const size_t obase = (size_t)q * K_N * (C_FEAT / 4);
  const int c4 = lane & 31;
  const int khalf = lane >> 5;
#pragma unroll
  for (int kk = 0; kk < K_N; kk += 2) {
    const int k = kk + khalf;
    const int id = idxs[wv][k];
    const float4 v = f4[fbase + (size_t)id * (C_FEAT / 4) + c4];
    o4[obase + (size_t)k * (C_FEAT / 4) + c4] = v;
  }
}

extern "C" void kernel_launch(void* const* d_in, const int* in_sizes, int n_in,
                              void* d_out, int out_size, void* d_ws,
                              size_t ws_size, hipStream_t stream) {
  const float* xyz = (const float*)d_in[0];
  const float* feat = (const float*)d_in[1];
  float* sample_xyz = (float*)d_out;
  float* out_feat = (float*)d_out + (size_t)B_SZ * K_S * 3;
  char* ws = (char*)d_ws;

  hipLaunchKernelGGL(bucket_kernel, dim3(B_SZ), dim3(1024), 0, stream, xyz, ws);
  hipLaunchKernelGGL(fps_kernel, dim3(B_SZ), dim3(FT), 0, stream, ws,
                     sample_xyz);
  hipLaunchKernelGGL(group_kernel, dim3((B_SZ * K_S) / 4), dim3(256), 0,
                     stream, xyz, feat, sample_xyz, out_feat);
}